// Round 9
// baseline (110.079 us; speedup 1.0000x reference)
//
#include <hip/hip_runtime.h>
#include <math.h>

namespace {

typedef float f32x2 __attribute__((ext_vector_type(2)));

constexpr int B_TOTAL = 131072;
constexpr int T_STEPS = 32;
constexpr int EPB     = 64;      // elements per block; 256 thr = 4 waves share 64 elems

constexpr double dG   = 9.81;
constexpr double dM   = 0.1667;
constexpr double dCAF = 5.0 * 0.25 * dM * dG;
constexpr double dCAR = dCAF;
constexpr double dLF  = 0.09 - 0.036;
constexpr double dLR  = 0.036;
constexpr double dIZ  = 0.000267;

constexpr float A33N = (float)(-(2.0 * dCAF + 2.0 * dCAR));
constexpr float A35N = (float)(-(2.0 * dCAF * dLF - 2.0 * dCAR * dLR));
constexpr float A53N = (float)(-(2.0 * dLF * dCAF - 2.0 * dLR * dCAR));
constexpr float A55N = (float)(-(2.0 * dLF * dLF * dCAF + 2.0 * dLR * dLR * dCAR));
constexpr float ST1  = (float)(2.0 * dCAF / dM);
constexpr float ST5  = (float)(2.0 * dLF * dCAF / dIZ);
constexpr float MF   = (float)dM;
constexpr float IZF  = (float)dIZ;
constexpr float R0M  = (float)(0.05 * dG / dM);
constexpr float R1M  = (float)(0.05 * dG / dM);
constexpr float R2I  = (float)(0.05 * dG * 0.2 / dIZ);
constexpr float THR_OFF = 0.24f;
constexpr float THR_RAT = 6.98f;
constexpr float DT    = 0.01f;
constexpr float PI_F  = (float)3.14159265358979323846;
constexpr float TWOPI = (float)(2.0 * 3.14159265358979323846);
constexpr float INV2PI = (float)(1.0 / (2.0 * 3.14159265358979323846));
constexpr float TWO_LOG2E = 2.8853900817779268f;   // 2*log2(e)

// tanh(x) = 1 - 2/(e+1), e = 2^(x*2*log2e). x->+inf: 1; x->-inf: -1.
__device__ __forceinline__ float fast_tanh(float x) {
    const float e = __builtin_amdgcn_exp2f(x * TWO_LOG2E);
    return fmaf(-2.0f, __builtin_amdgcn_rcpf(e + 1.0f), 1.0f);
}

// packed f32: 2 exact f32 FMAs per issue slot; weight operand wave-uniform -> SGPR pair.
__device__ __forceinline__ void pk_fma(f32x2& acc, f32x2 x, f32x2 w) {
    asm("v_pk_fma_f32 %0, %1, %2, %0" : "+v"(acc) : "v"(x), "s"(w));
}

// LDS swizzle: float-element e (0..31) within row r (XOR touches bits 2..4 only).
__device__ __forceinline__ int swz(int row, int e) { return e ^ ((row & 7) << 2); }

__global__ __launch_bounds__(256, 7)
void rollout_kernel(const float* __restrict__ fs,     // B x 4 x 8
                    const float* __restrict__ acts,   // B x 32 x 2
                    const float* __restrict__ w1g,    // 16 x 32
                    const float* __restrict__ b1g,    // 16
                    const float* __restrict__ w2g,    // 3 x 16
                    const float* __restrict__ b2g,    // 3
                    const int*   __restrict__ en,     // 1
                    float*       __restrict__ out)    // B x 32 x 8
{
    __shared__ float sbuf[EPB * 32];          // 8 KB: init-state / output staging
    __shared__ float abuf[EPB * 32];          // 8 KB: actions, 16 steps
    __shared__ float xbuf[2][3][4][64];       // 6 KB: [parity][comp][h][lane]

    const int tid = threadIdx.x;
    const int h   = tid >> 6;                 // wave 0..3 -> layer-1 rows h*4..h*4+3
    const int hu  = __builtin_amdgcn_readfirstlane(h);  // provably wave-uniform
    const int l   = tid & 63;                 // element within block
    const size_t blk_base = (size_t)blockIdx.x * EPB;

    // ---- coalesced load of the block's 64x32 init-state region ----
    {
        const float4* fsb = reinterpret_cast<const float4*>(fs + blk_base * 32);
        #pragma unroll
        for (int k = 0; k < 2; ++k) {
            const int q   = k * 256 + tid;
            const int row = q >> 3;
            const int e   = (q & 7) << 2;
            *reinterpret_cast<float4*>(&sbuf[row * 32 + swz(row, e)]) = fsb[q];
        }
    }
    __syncthreads();

    // 4-timestep window as 16 f32 pairs, statically rotated (oldest group = t&3).
    // All 4 waves hold identical full windows for their 64 shared elements.
    // Current state is aliased to the newest group (no separate s0..s5 carry).
    f32x2 wp[16];
    #pragma unroll
    for (int i = 0; i < 8; ++i) {
        const float4 v = *reinterpret_cast<const float4*>(&sbuf[l * 32 + swz(l, 4 * i)]);
        wp[2*i].x   = v.x; wp[2*i].y   = v.y;
        wp[2*i+1].x = v.z; wp[2*i+1].y = v.w;
    }
    __syncthreads();   // all waves must finish reading before staging overwrites

    const int rnn = *en;

    // biases folded into accumulator inits (pairs {b,0}); layer-2 bias only on h=0
    f32x2 bp1[4];
    #pragma unroll
    for (int j = 0; j < 4; ++j) { bp1[j].x = b1g[hu * 4 + j]; bp1[j].y = 0.0f; }
    f32x2 bp2[3];
    #pragma unroll
    for (int c3 = 0; c3 < 3; ++c3) { bp2[c3].x = hu ? 0.0f : b2g[c3]; bp2[c3].y = 0.0f; }

    const f32x2* w1p = reinterpret_cast<const f32x2*>(w1g);  // 16 rows x 16 pairs
    const f32x2* w2p = reinterpret_cast<const f32x2*>(w2g);  // 3 rows x 8 pairs

    // opaque uniform offset: keeps per-step weight loads inside the loop.
    int o1 = 0;

    for (int tc = 0; tc < T_STEPS; tc += 4) {
        if ((tc & 15) == 0) {
            // ---- coalesced action staging: 16 steps = 128 B/row ----
            #pragma unroll
            for (int k = 0; k < 2; ++k) {
                const int q   = k * 256 + tid;
                const int row = q >> 3;
                const int e   = (q & 7) << 2;
                const float4 v = *reinterpret_cast<const float4*>(
                    &acts[(blk_base + row) * 64 + tc * 2 + e]);
                *reinterpret_cast<float4*>(&abuf[row * 32 + swz(row, e)]) = v;
            }
            __syncthreads();
        }

        #pragma unroll
        for (int tl = 0; tl < 4; ++tl) {
            const int t = tc + tl;
            asm volatile("" : "+s"(o1));

            // current state = newest window group (pure register aliases)
            const int gp = ((tl + 3) & 3) << 2;
            const float s0v = wp[gp].x,   s1v = wp[gp].y;
            const float s2v = wp[gp+1].x, s3v = wp[gp+1].y;
            const float s4v = wp[gp+2].x, s5v = wp[gp+2].y;
            const float thr = wp[gp+3].x, steer = wp[gp+3].y;

            float sn, c;
            __sincosf(s4v, &sn, &c);

            const float Vx = s1v * c + s3v * sn;
            const float v3 = c * s3v - sn * s1v;
            const float v5 = s5v;

            const float inv_mvx  = __builtin_amdgcn_rcpf(MF * Vx);
            const float inv_izvx = __builtin_amdgcn_rcpf(IZF * Vx);
            const float a33 = A33N * inv_mvx;
            const float a35 = -Vx + A35N * inv_mvx;
            const float a53 = A53N * inv_izvx;
            const float a55 = A55N * inv_izvx;

            const float d0 = Vx;
            float       d1 = (thr - THR_OFF) * THR_RAT;
            const float d2 = v3;
            float       d3 = a33 * v3 + a35 * v5 + ST1 * steer;
            const float d4 = v5;
            float       d5 = a53 * v3 + a55 * v5 + ST5 * steer;

            const float2 act = *reinterpret_cast<const float2*>(
                &abuf[l * 32 + swz(l, 2 * (t & 15))]);

            if (rnn) {
                // ---- layer 1: this WAVE computes rows hu*4 .. hu*4+3 (weights scalar) ----
                const f32x2* __restrict__ wrb = w1p + o1 + hu * 64;
                float y1[4];
                #pragma unroll
                for (int jj = 0; jj < 4; ++jj) {
                    const f32x2* __restrict__ wr = wrb + jj * 16;
                    f32x2 acc = bp1[jj];
                    #pragma unroll
                    for (int i = 0; i < 16; ++i) {
                        const int phys = (((tl + (i >> 2)) & 3) << 2) | (i & 3);
                        pk_fma(acc, wp[phys], wr[i]);
                    }
                    y1[jj] = fast_tanh(acc.x + acc.y);
                }
                f32x2 y1p[2];
                y1p[0].x = y1[0]; y1p[0].y = y1[1];
                y1p[1].x = y1[2]; y1p[1].y = y1[3];

                // ---- layer 2: 2-pair partial per wave, 4-way exchange via LDS ----
                const f32x2* __restrict__ w2r = w2p + o1 + hu * 2;
                f32x2 q0 = bp2[0], q1 = bp2[1], q2 = bp2[2];
                #pragma unroll
                for (int i = 0; i < 2; ++i) {
                    pk_fma(q0, y1p[i], w2r[i]);
                    pk_fma(q1, y1p[i], w2r[8 + i]);
                    pk_fma(q2, y1p[i], w2r[16 + i]);
                }

                const int p = tl & 1;          // parity double-buffer -> 1 barrier/step
                xbuf[p][0][h][l] = q0.x + q0.y;
                xbuf[p][1][h][l] = q1.x + q1.y;
                xbuf[p][2][h][l] = q2.x + q2.y;
                __syncthreads();
                // fixed summation tree, identical LDS values in all waves -> bitwise-identical z
                const float z0 = (xbuf[p][0][0][l] + xbuf[p][0][1][l]) + (xbuf[p][0][2][l] + xbuf[p][0][3][l]);
                const float z1 = (xbuf[p][1][0][l] + xbuf[p][1][1][l]) + (xbuf[p][1][2][l] + xbuf[p][1][3][l]);
                const float z2 = (xbuf[p][2][0][l] + xbuf[p][2][1][l]) + (xbuf[p][2][2][l] + xbuf[p][2][3][l]);

                d1 += fast_tanh(z0) * R0M;
                d3 += fast_tanh(z1) * R1M;
                d5 += fast_tanh(z2) * R2I;
            }

            const float ns0 = s0v + (c * d0 - sn * d2) * DT;
            const float ns1 = s1v + (c * d1 - sn * d3) * DT;
            const float ns2 = s2v + (sn * d0 + c * d2) * DT;
            const float ns3 = s3v + (sn * d1 + c * d3) * DT;
            float aa = s4v + d4 * DT + PI_F;
            aa = aa - floorf(aa * INV2PI) * TWOPI;
            const float ns4 = aa - PI_F;
            const float ns5 = s5v + d5 * DT;

            // stage this step's 8 outputs: wave 0 writes lo float4, wave 2 hi
            if ((h & 1) == 0) {
                const float4 v = (h == 0) ? make_float4(ns0, ns1, ns2, ns3)
                                          : make_float4(ns4, ns5, act.x, act.y);
                *reinterpret_cast<float4*>(&sbuf[l * 32 + swz(l, tl * 8 + (h & 2) * 2)]) = v;
            }

            // overwrite oldest window slot (group tl&3) with the new timestep
            {
                const int g = (tl & 3) << 2;
                wp[g+0].x = ns0;  wp[g+0].y = ns1;
                wp[g+1].x = ns2;  wp[g+1].y = ns3;
                wp[g+2].x = ns4;  wp[g+2].y = ns5;
                wp[g+3].x = act.x; wp[g+3].y = act.y;
            }
        }

        // ---- flush 4-step chunk: full 128-B lines per 8-lane group ----
        __syncthreads();
        #pragma unroll
        for (int k = 0; k < 2; ++k) {
            const int q   = k * 256 + tid;
            const int row = q >> 3;
            const int e   = (q & 7) << 2;
            const float4 v = *reinterpret_cast<const float4*>(&sbuf[row * 32 + swz(row, e)]);
            *reinterpret_cast<float4*>(&out[(blk_base + row) * 256 + tc * 8 + e]) = v;
        }
        __syncthreads();
    }
}

} // namespace

extern "C" void kernel_launch(void* const* d_in, const int* in_sizes, int n_in,
                              void* d_out, int out_size, void* d_ws, size_t ws_size,
                              hipStream_t stream) {
    const float* fs = (const float*)d_in[0];
    const float* ac = (const float*)d_in[1];
    const float* w1 = (const float*)d_in[2];
    const float* b1 = (const float*)d_in[3];
    const float* w2 = (const float*)d_in[4];
    const float* b2 = (const float*)d_in[5];
    const int*   en = (const int*)d_in[6];
    float* out = (float*)d_out;

    dim3 grid(B_TOTAL / EPB), block(256);
    hipLaunchKernelGGL(rollout_kernel, grid, block, 0, stream,
                       fs, ac, w1, b1, w2, b2, en, out);
}

// Round 11
// 74.566 us; speedup vs baseline: 1.4763x; 1.4763x over previous
//
#include <hip/hip_runtime.h>
#include <math.h>

namespace {

typedef short  bf16x8 __attribute__((ext_vector_type(8)));
typedef float  f32x4  __attribute__((ext_vector_type(4)));

constexpr int B_TOTAL = 131072;
constexpr int T_STEPS = 32;

constexpr double dG   = 9.81;
constexpr double dM   = 0.1667;
constexpr double dCAF = 5.0 * 0.25 * dM * dG;
constexpr double dCAR = dCAF;
constexpr double dLF  = 0.09 - 0.036;
constexpr double dLR  = 0.036;
constexpr double dIZ  = 0.000267;

constexpr float A33N = (float)(-(2.0 * dCAF + 2.0 * dCAR));
constexpr float A35N = (float)(-(2.0 * dCAF * dLF - 2.0 * dCAR * dLR));
constexpr float A53N = (float)(-(2.0 * dLF * dCAF - 2.0 * dLR * dCAR));
constexpr float A55N = (float)(-(2.0 * dLF * dLF * dCAF + 2.0 * dLR * dLR * dCAR));
constexpr float ST1  = (float)(2.0 * dCAF / dM);
constexpr float ST5  = (float)(2.0 * dLF * dCAF / dIZ);
constexpr float MF   = (float)dM;
constexpr float IZF  = (float)dIZ;
constexpr float R0M  = (float)(0.05 * dG / dM);
constexpr float R1M  = (float)(0.05 * dG / dM);
constexpr float R2I  = (float)(0.05 * dG * 0.2 / dIZ);
constexpr float THR_OFF = 0.24f;
constexpr float THR_RAT = 6.98f;
constexpr float DT    = 0.01f;
constexpr float PI_F  = (float)3.14159265358979323846;
constexpr float TWOPI = (float)(2.0 * 3.14159265358979323846);
constexpr float INV2PI = (float)(1.0 / (2.0 * 3.14159265358979323846));
constexpr float TWO_LOG2E = 2.8853900817779268f;

__device__ __forceinline__ float fast_tanh(float x) {
    const float e = __builtin_amdgcn_exp2f(x * TWO_LOG2E);
    return fmaf(-2.0f, __builtin_amdgcn_rcpf(e + 1.0f), 1.0f);
}

__device__ __forceinline__ unsigned bf16_rne_u(float f) {
    unsigned u = __float_as_uint(f);
    return (u + 0x7fffu + ((u >> 16) & 1u)) >> 16;
}

__device__ __forceinline__ unsigned pk_bf16(float lo, float hi) {
    unsigned r;
    asm("v_cvt_pk_bf16_f32 %0, %1, %2" : "=v"(r) : "v"(lo), "v"(hi));
    return r;
}
__device__ __forceinline__ float bfl(unsigned p) { return __uint_as_float(p << 16); }
__device__ __forceinline__ float bfh(unsigned p) { return __uint_as_float(p & 0xffff0000u); }

union U4F { uint4 u; bf16x8 f; };

// ---- prep: A-fragments (W1 16x32) for 4 rotations x 3 split levels.
// lane L: row L&15, k = 8*(L>>4)+j. variant p: k-group g holds pos (g-p)&3.
__global__ void prep_kernel(const float* __restrict__ w1, unsigned* __restrict__ ws) {
    const int i = threadIdx.x;
    if (i >= 256) return;
    const int p = i >> 6, L = i & 63;
    const int row = L & 15, g = L >> 4;
    const int pos = (g - p) & 3;
    unsigned hd[4], md[4], ld[4];
    #pragma unroll
    for (int d = 0; d < 4; ++d) {
        unsigned hh[2], mm[2], ll[2];
        #pragma unroll
        for (int s = 0; s < 2; ++s) {
            const float v = w1[row * 32 + pos * 8 + 2 * d + s];
            const unsigned h = bf16_rne_u(v);
            const float r1 = v - __uint_as_float(h << 16);
            const unsigned m = bf16_rne_u(r1);
            const float r2 = r1 - __uint_as_float(m << 16);
            const unsigned l = bf16_rne_u(r2);
            hh[s] = h; mm[s] = m; ll[s] = l;
        }
        hd[d] = hh[0] | (hh[1] << 16);
        md[d] = mm[0] | (mm[1] << 16);
        ld[d] = ll[0] | (ll[1] << 16);
    }
    uint4* w4 = reinterpret_cast<uint4*>(ws);
    w4[(p * 3 + 0) * 64 + L] = make_uint4(hd[0], hd[1], hd[2], hd[3]);
    w4[(p * 3 + 1) * 64 + L] = make_uint4(md[0], md[1], md[2], md[3]);
    w4[(p * 3 + 2) * 64 + L] = make_uint4(ld[0], ld[1], ld[2], ld[3]);
}

// X-tile byte addressing (element e row = 64 B; slot s16 = s*16 bytes)
__device__ __forceinline__ int xoff(int e, int s16) {
    return (e * 64 + s16) ^ ((e & 7) << 4);
}

// 3-level split of one timestep row (8 f32) -> Xh/Xm/Xl at slot
__device__ __forceinline__ void split3_store(
    unsigned short* Xh, unsigned short* Xm, unsigned short* Xl, int L, int slot,
    float v0, float v1, float v2, float v3, float v4, float v5, float v6, float v7)
{
    const unsigned h0 = pk_bf16(v0, v1), h1 = pk_bf16(v2, v3);
    const unsigned h2 = pk_bf16(v4, v5), h3 = pk_bf16(v6, v7);
    const float r0 = v0 - bfl(h0), r1 = v1 - bfh(h0);
    const float r2 = v2 - bfl(h1), r3 = v3 - bfh(h1);
    const float r4 = v4 - bfl(h2), r5 = v5 - bfh(h2);
    const float r6 = v6 - bfl(h3), r7 = v7 - bfh(h3);
    const unsigned m0 = pk_bf16(r0, r1), m1 = pk_bf16(r2, r3);
    const unsigned m2 = pk_bf16(r4, r5), m3 = pk_bf16(r6, r7);
    const unsigned l0 = pk_bf16(r0 - bfl(m0), r1 - bfh(m0));
    const unsigned l1 = pk_bf16(r2 - bfl(m1), r3 - bfh(m1));
    const unsigned l2 = pk_bf16(r4 - bfl(m2), r5 - bfh(m2));
    const unsigned l3 = pk_bf16(r6 - bfl(m3), r7 - bfh(m3));
    const int off = xoff(L, slot * 16);
    *reinterpret_cast<uint4*>((char*)Xh + off) = make_uint4(h0, h1, h2, h3);
    *reinterpret_cast<uint4*>((char*)Xm + off) = make_uint4(m0, m1, m2, m3);
    *reinterpret_cast<uint4*>((char*)Xl + off) = make_uint4(l0, l1, l2, l3);
}

__global__ __launch_bounds__(64, 2)
void rollout_kernel(const float* __restrict__ fs,     // B x 4 x 8
                    const float* __restrict__ acts,   // B x 32 x 2
                    const unsigned* __restrict__ ws,  // A-fragments (prep)
                    const float* __restrict__ b1g,    // 16
                    const float* __restrict__ w2g,    // 3 x 16
                    const float* __restrict__ b2g,    // 3
                    const int*   __restrict__ en,     // 1
                    float*       __restrict__ out)    // B x 32 x 8
{
    __shared__ unsigned short Xh[2048];   // 4 KB  window hi
    __shared__ unsigned short Xm[2048];   // 4 KB  window mid
    __shared__ unsigned short Xl[2048];   // 4 KB  window lo
    __shared__ float abuf[64 * 8];        // 2 KB  actions, 4 steps
    __shared__ float sbuf[64 * 16];       // 4 KB  outputs, 2 steps
    // total 18 KB -> 8 single-wave blocks/CU

    const int L = threadIdx.x;            // lane = owned element
    const int g = L >> 4;                 // k-group / D-row-group
    const size_t blk = (size_t)blockIdx.x * 64;

    const int rnn = *en;

    // ---- loop-invariant registers ----
    bf16x8 Ah[4], Am[4], Al[4];
    {
        const uint4* w4 = reinterpret_cast<const uint4*>(ws);
        #pragma unroll
        for (int p = 0; p < 4; ++p) {
            U4F a; a.u = w4[(p * 3 + 0) * 64 + L]; Ah[p] = a.f;
            U4F b; b.u = w4[(p * 3 + 1) * 64 + L]; Am[p] = b.f;
            U4F c; c.u = w4[(p * 3 + 2) * 64 + L]; Al[p] = c.f;
        }
    }
    float b1s[4];
    #pragma unroll
    for (int r = 0; r < 4; ++r) b1s[r] = b1g[g * 4 + r];
    float w2s[3][4];
    #pragma unroll
    for (int c = 0; c < 3; ++c)
        #pragma unroll
        for (int r = 0; r < 4; ++r) w2s[c][r] = w2g[c * 16 + g * 4 + r];
    const float bias2_0 = b2g[0], bias2_1 = b2g[1], bias2_2 = b2g[2];

    // ---- init: own element's 4 history rows -> X tiles + state regs ----
    float s0, s1, s2, s3, s4, s5, thr, steer;
    {
        const float4* ip = reinterpret_cast<const float4*>(fs + (blk + L) * 32);
        #pragma unroll
        for (int rr = 0; rr < 4; ++rr) {
            const float4 va = ip[rr * 2], vb = ip[rr * 2 + 1];
            split3_store(Xh, Xm, Xl, L, rr, va.x, va.y, va.z, va.w, vb.x, vb.y, vb.z, vb.w);
            if (rr == 3) {
                s0 = va.x; s1 = va.y; s2 = va.z; s3 = va.w;
                s4 = vb.x; s5 = vb.y; thr = vb.z; steer = vb.w;
            }
        }
    }

    const f32x4 zero4 = {0.f, 0.f, 0.f, 0.f};
    const bool bb0 = (g & 1) != 0, bb1 = (g & 2) != 0;

    for (int tc = 0; tc < T_STEPS; tc += 4) {
        // ---- coalesced action staging: 4 steps = 32 B/row ----
        #pragma unroll
        for (int k = 0; k < 2; ++k) {
            const int q   = k * 64 + L;
            const int row = q >> 1;
            const int f4  = q & 1;
            const float4 v = *reinterpret_cast<const float4*>(
                &acts[(blk + row) * 64 + tc * 2 + f4 * 4]);
            *reinterpret_cast<float4*>(&abuf[row * 8 + ((f4 * 4) ^ (row & 4))]) = v;
        }

        #pragma unroll
        for (int tl = 0; tl < 4; ++tl) {
            const float2 act = *reinterpret_cast<const float2*>(
                &abuf[L * 8 + ((2 * tl) ^ (L & 4))]);
            const float ax = act.x, ay = act.y;

            float sn, c;
            __sincosf(s4, &sn, &c);

            const float Vx = s1 * c + s3 * sn;
            const float v3 = c * s3 - sn * s1;
            const float v5 = s5;

            const float inv_mvx  = __builtin_amdgcn_rcpf(MF * Vx);
            const float inv_izvx = __builtin_amdgcn_rcpf(IZF * Vx);
            const float a33 = A33N * inv_mvx;
            const float a35 = -Vx + A35N * inv_mvx;
            const float a53 = A53N * inv_izvx;
            const float a55 = A55N * inv_izvx;

            const float d0 = Vx;
            float       d1 = (thr - THR_OFF) * THR_RAT;
            const float d2 = v3;
            float       d3 = a33 * v3 + a35 * v5 + ST1 * steer;
            const float d4 = v5;
            float       d5 = a53 * v3 + a55 * v5 + ST5 * steer;

            if (rnn) {
                // ---- layer 1 via MFMA, 3-level compensated (6 MFMA/tile) ----
                f32x4 acc[4];
                #pragma unroll
                for (int n = 0; n < 4; ++n) {
                    const int roff = xoff(16 * n + (L & 15), g * 16);
                    U4F bh; bh.u = *reinterpret_cast<const uint4*>((const char*)Xh + roff);
                    U4F bm; bm.u = *reinterpret_cast<const uint4*>((const char*)Xm + roff);
                    U4F bl; bl.u = *reinterpret_cast<const uint4*>((const char*)Xl + roff);
                    f32x4 a = __builtin_amdgcn_mfma_f32_16x16x32_bf16(Ah[tl], bl.f, zero4, 0, 0, 0);
                    a = __builtin_amdgcn_mfma_f32_16x16x32_bf16(Al[tl], bh.f, a, 0, 0, 0);
                    a = __builtin_amdgcn_mfma_f32_16x16x32_bf16(Am[tl], bm.f, a, 0, 0, 0);
                    a = __builtin_amdgcn_mfma_f32_16x16x32_bf16(Am[tl], bh.f, a, 0, 0, 0);
                    a = __builtin_amdgcn_mfma_f32_16x16x32_bf16(Ah[tl], bm.f, a, 0, 0, 0);
                    acc[n] = __builtin_amdgcn_mfma_f32_16x16x32_bf16(Ah[tl], bh.f, a, 0, 0, 0);
                }
                // y1 rows g*4+r per tile; layer-2 partials then transpose-reduce
                float p0[4], p1[4], p2[4];
                #pragma unroll
                for (int n = 0; n < 4; ++n) {
                    float q0 = 0.f, q1 = 0.f, q2 = 0.f;
                    #pragma unroll
                    for (int r = 0; r < 4; ++r) {
                        const float y = fast_tanh(acc[n][r] + b1s[r]);
                        q0 = fmaf(w2s[0][r], y, q0);
                        q1 = fmaf(w2s[1][r], y, q1);
                        q2 = fmaf(w2s[2][r], y, q2);
                    }
                    p0[n] = q0; p1[n] = q1; p2[n] = q2;
                }
                float z0, z1, z2;
                #pragma unroll
                for (int c3 = 0; c3 < 3; ++c3) {
                    const float* p = (c3 == 0) ? p0 : (c3 == 1) ? p1 : p2;
                    const float own = bb1 ? (bb0 ? p[3] : p[2]) : (bb0 ? p[1] : p[0]);
                    const float x1  = bb1 ? (bb0 ? p[2] : p[3]) : (bb0 ? p[0] : p[1]);
                    const float x2  = bb1 ? (bb0 ? p[1] : p[0]) : (bb0 ? p[3] : p[2]);
                    const float x3  = bb1 ? (bb0 ? p[0] : p[1]) : (bb0 ? p[2] : p[3]);
                    const float a = own + __shfl_xor(x1, 16, 64);
                    const float b = x2  + __shfl_xor(x3, 16, 64);
                    const float T = a + __shfl_xor(b, 32, 64);
                    if (c3 == 0) z0 = T; else if (c3 == 1) z1 = T; else z2 = T;
                }
                d1 += fast_tanh(z0 + bias2_0) * R0M;
                d3 += fast_tanh(z1 + bias2_1) * R1M;
                d5 += fast_tanh(z2 + bias2_2) * R2I;
            }

            const float ns0 = s0 + (c * d0 - sn * d2) * DT;
            const float ns1 = s1 + (c * d1 - sn * d3) * DT;
            const float ns2 = s2 + (sn * d0 + c * d2) * DT;
            const float ns3 = s3 + (sn * d1 + c * d3) * DT;
            float aa = s4 + d4 * DT + PI_F;
            aa = aa - floorf(aa * INV2PI) * TWOPI;
            const float ns4 = aa - PI_F;
            const float ns5 = s5 + d5 * DT;

            // stage outputs (elem-major, xor-swizzled float4 slots)
            const int c4b = (tl & 1) * 2;
            *reinterpret_cast<float4*>(&sbuf[L * 16 + 4 * ((c4b + 0) ^ (L & 3))]) =
                make_float4(ns0, ns1, ns2, ns3);
            *reinterpret_cast<float4*>(&sbuf[L * 16 + 4 * ((c4b + 1) ^ (L & 3))]) =
                make_float4(ns4, ns5, ax, ay);

            if (rnn) {
                split3_store(Xh, Xm, Xl, L, tl, ns0, ns1, ns2, ns3, ns4, ns5, ax, ay);
            }

            s0 = ns0; s1 = ns1; s2 = ns2; s3 = ns3;
            s4 = ns4; s5 = ns5; thr = ax; steer = ay;

            // ---- flush 2-step chunk (64 B/elem; L2 merges adjacent chunks) ----
            if (tl & 1) {
                const int t2 = tc + tl - 1;
                #pragma unroll
                for (int k = 0; k < 4; ++k) {
                    const int q   = k * 64 + L;
                    const int row = q >> 2;
                    const int f   = q & 3;
                    const float4 v = *reinterpret_cast<const float4*>(
                        &sbuf[row * 16 + 4 * (f ^ (row & 3))]);
                    *reinterpret_cast<float4*>(&out[(blk + row) * 256 + t2 * 8 + f * 4]) = v;
                }
            }
        }
    }
}

} // namespace

extern "C" void kernel_launch(void* const* d_in, const int* in_sizes, int n_in,
                              void* d_out, int out_size, void* d_ws, size_t ws_size,
                              hipStream_t stream) {
    const float* fs = (const float*)d_in[0];
    const float* ac = (const float*)d_in[1];
    const float* w1 = (const float*)d_in[2];
    const float* b1 = (const float*)d_in[3];
    const float* w2 = (const float*)d_in[4];
    const float* b2 = (const float*)d_in[5];
    const int*   en = (const int*)d_in[6];
    float* out = (float*)d_out;
    unsigned* ws = (unsigned*)d_ws;

    hipLaunchKernelGGL(prep_kernel, dim3(1), dim3(256), 0, stream, w1, ws);

    dim3 grid(B_TOTAL / 64), block(64);
    hipLaunchKernelGGL(rollout_kernel, grid, block, 0, stream,
                       fs, ac, ws, b1, w2, b2, en, out);
}

// Round 12
// 74.374 us; speedup vs baseline: 1.4801x; 1.0026x over previous
//
#include <hip/hip_runtime.h>
#include <math.h>

namespace {

typedef short  bf16x8 __attribute__((ext_vector_type(8)));
typedef float  f32x4  __attribute__((ext_vector_type(4)));

constexpr int B_TOTAL = 131072;
constexpr int T_STEPS = 32;

constexpr double dG   = 9.81;
constexpr double dM   = 0.1667;
constexpr double dCAF = 5.0 * 0.25 * dM * dG;
constexpr double dCAR = dCAF;
constexpr double dLF  = 0.09 - 0.036;
constexpr double dLR  = 0.036;
constexpr double dIZ  = 0.000267;

constexpr float A33N = (float)(-(2.0 * dCAF + 2.0 * dCAR));
constexpr float A35N = (float)(-(2.0 * dCAF * dLF - 2.0 * dCAR * dLR));
constexpr float A53N = (float)(-(2.0 * dLF * dCAF - 2.0 * dLR * dCAR));
constexpr float A55N = (float)(-(2.0 * dLF * dLF * dCAF + 2.0 * dLR * dLR * dCAR));
constexpr float ST1  = (float)(2.0 * dCAF / dM);
constexpr float ST5  = (float)(2.0 * dLF * dCAF / dIZ);
constexpr float MF   = (float)dM;
constexpr float IZF  = (float)dIZ;
constexpr float R0M  = (float)(0.05 * dG / dM);
constexpr float R1M  = (float)(0.05 * dG / dM);
constexpr float R2I  = (float)(0.05 * dG * 0.2 / dIZ);
constexpr float THR_OFF = 0.24f;
constexpr float THR_RAT = 6.98f;
constexpr float DT    = 0.01f;
constexpr float PI_F  = (float)3.14159265358979323846;
constexpr float TWOPI = (float)(2.0 * 3.14159265358979323846);
constexpr float INV2PI = (float)(1.0 / (2.0 * 3.14159265358979323846));
constexpr float TWO_LOG2E = 2.8853900817779268f;

__device__ __forceinline__ float fast_tanh(float x) {
    const float e = __builtin_amdgcn_exp2f(x * TWO_LOG2E);
    return fmaf(-2.0f, __builtin_amdgcn_rcpf(e + 1.0f), 1.0f);
}

__device__ __forceinline__ unsigned bf16_rne_u(float f) {
    unsigned u = __float_as_uint(f);
    return (u + 0x7fffu + ((u >> 16) & 1u)) >> 16;
}

__device__ __forceinline__ unsigned pk_bf16(float lo, float hi) {
    unsigned r;
    asm("v_cvt_pk_bf16_f32 %0, %1, %2" : "=v"(r) : "v"(lo), "v"(hi));
    return r;
}
__device__ __forceinline__ float bfl(unsigned p) { return __uint_as_float(p << 16); }
__device__ __forceinline__ float bfh(unsigned p) { return __uint_as_float(p & 0xffff0000u); }

union U4F { uint4 u; bf16x8 f; };

// ---- prep: A-fragments (W1 16x32) for 4 rotations x 3 split levels.
// lane L: row L&15, k = 8*(L>>4)+j. variant p: k-group g holds pos (g-p)&3.
__global__ void prep_kernel(const float* __restrict__ w1, unsigned* __restrict__ ws) {
    const int i = threadIdx.x;
    if (i >= 256) return;
    const int p = i >> 6, L = i & 63;
    const int row = L & 15, g = L >> 4;
    const int pos = (g - p) & 3;
    unsigned hd[4], md[4], ld[4];
    #pragma unroll
    for (int d = 0; d < 4; ++d) {
        unsigned hh[2], mm[2], ll[2];
        #pragma unroll
        for (int s = 0; s < 2; ++s) {
            const float v = w1[row * 32 + pos * 8 + 2 * d + s];
            const unsigned h = bf16_rne_u(v);
            const float r1 = v - __uint_as_float(h << 16);
            const unsigned m = bf16_rne_u(r1);
            const float r2 = r1 - __uint_as_float(m << 16);
            const unsigned l = bf16_rne_u(r2);
            hh[s] = h; mm[s] = m; ll[s] = l;
        }
        hd[d] = hh[0] | (hh[1] << 16);
        md[d] = mm[0] | (mm[1] << 16);
        ld[d] = ll[0] | (ll[1] << 16);
    }
    uint4* w4 = reinterpret_cast<uint4*>(ws);
    w4[(p * 3 + 0) * 64 + L] = make_uint4(hd[0], hd[1], hd[2], hd[3]);
    w4[(p * 3 + 1) * 64 + L] = make_uint4(md[0], md[1], md[2], md[3]);
    w4[(p * 3 + 2) * 64 + L] = make_uint4(ld[0], ld[1], ld[2], ld[3]);
}

// X-tile byte offset within one level (element e, slot-bytes s16):
// base(e) = (e*64) ^ ((e&7)<<4); slot bits (4-5) are disjoint from the
// XOR mask's effect on bit 6 and base bits, so off = base ^ s16.
__device__ __forceinline__ int xbase(int e) { return (e * 64) ^ ((e & 7) << 4); }

// 3-level split of one timestep row (8 f32) -> X (hi +0, mid +4096, lo +8192)
__device__ __forceinline__ void split3_store(
    char* X, int off,
    float v0, float v1, float v2, float v3, float v4, float v5, float v6, float v7)
{
    const unsigned h0 = pk_bf16(v0, v1), h1 = pk_bf16(v2, v3);
    const unsigned h2 = pk_bf16(v4, v5), h3 = pk_bf16(v6, v7);
    const float r0 = v0 - bfl(h0), r1 = v1 - bfh(h0);
    const float r2 = v2 - bfl(h1), r3 = v3 - bfh(h1);
    const float r4 = v4 - bfl(h2), r5 = v5 - bfh(h2);
    const float r6 = v6 - bfl(h3), r7 = v7 - bfh(h3);
    const unsigned m0 = pk_bf16(r0, r1), m1 = pk_bf16(r2, r3);
    const unsigned m2 = pk_bf16(r4, r5), m3 = pk_bf16(r6, r7);
    const unsigned l0 = pk_bf16(r0 - bfl(m0), r1 - bfh(m0));
    const unsigned l1 = pk_bf16(r2 - bfl(m1), r3 - bfh(m1));
    const unsigned l2 = pk_bf16(r4 - bfl(m2), r5 - bfh(m2));
    const unsigned l3 = pk_bf16(r6 - bfl(m3), r7 - bfh(m3));
    *reinterpret_cast<uint4*>(X + off)        = make_uint4(h0, h1, h2, h3);
    *reinterpret_cast<uint4*>(X + 4096 + off) = make_uint4(m0, m1, m2, m3);
    *reinterpret_cast<uint4*>(X + 8192 + off) = make_uint4(l0, l1, l2, l3);
}

__global__ __launch_bounds__(64, 2)
void rollout_kernel(const float* __restrict__ fs,     // B x 4 x 8
                    const float* __restrict__ acts,   // B x 32 x 2
                    const unsigned* __restrict__ ws,  // A-fragments (prep)
                    const float* __restrict__ b1g,    // 16
                    const float* __restrict__ w2g,    // 3 x 16
                    const float* __restrict__ b2g,    // 3
                    const int*   __restrict__ en,     // 1
                    float*       __restrict__ out)    // B x 32 x 8
{
    __shared__ char  X[12288];            // 12 KB window: hi | mid | lo
    __shared__ float abuf[64 * 8];        // 2 KB  actions, 4 steps
    __shared__ float sbuf[64 * 16];       // 4 KB  outputs, 2 steps
    // total 18 KB -> 8 single-wave blocks/CU

    const int L = threadIdx.x;            // lane = owned element
    const int g = L >> 4;                 // k-group / D-row-group
    const size_t blk = (size_t)blockIdx.x * 64;

    const int rnn = *en;

    // ---- loop-invariant registers ----
    bf16x8 Ah[4], Am[4], Al[4];
    {
        const uint4* w4 = reinterpret_cast<const uint4*>(ws);
        #pragma unroll
        for (int p = 0; p < 4; ++p) {
            U4F a; a.u = w4[(p * 3 + 0) * 64 + L]; Ah[p] = a.f;
            U4F b; b.u = w4[(p * 3 + 1) * 64 + L]; Am[p] = b.f;
            U4F c; c.u = w4[(p * 3 + 2) * 64 + L]; Al[p] = c.f;
        }
    }
    float b1s[4];
    #pragma unroll
    for (int r = 0; r < 4; ++r) b1s[r] = b1g[g * 4 + r];
    float w2s[3][4];
    #pragma unroll
    for (int c = 0; c < 3; ++c)
        #pragma unroll
        for (int r = 0; r < 4; ++r) w2s[c][r] = w2g[c * 16 + g * 4 + r];
    const float bias2_0 = b2g[0], bias2_1 = b2g[1], bias2_2 = b2g[2];

    // hoisted LDS offsets (constant over the whole t-loop)
    int roffv[4];
    #pragma unroll
    for (int n = 0; n < 4; ++n) roffv[n] = xbase(16 * n + (L & 15)) ^ (g * 16);
    const int wboff = xbase(L);

    // ---- init: own element's 4 history rows -> X tiles + state regs ----
    float s0, s1, s2, s3, s4, s5, thr, steer;
    {
        const float4* ip = reinterpret_cast<const float4*>(fs + (blk + L) * 32);
        #pragma unroll
        for (int rr = 0; rr < 4; ++rr) {
            const float4 va = ip[rr * 2], vb = ip[rr * 2 + 1];
            split3_store(X, wboff ^ (rr * 16), va.x, va.y, va.z, va.w, vb.x, vb.y, vb.z, vb.w);
            if (rr == 3) {
                s0 = va.x; s1 = va.y; s2 = va.z; s3 = va.w;
                s4 = vb.x; s5 = vb.y; thr = vb.z; steer = vb.w;
            }
        }
    }

    const f32x4 zero4 = {0.f, 0.f, 0.f, 0.f};
    const bool bb0 = (g & 1) != 0, bb1 = (g & 2) != 0;

    for (int tc = 0; tc < T_STEPS; tc += 4) {
        // ---- coalesced action staging: 4 steps = 32 B/row ----
        #pragma unroll
        for (int k = 0; k < 2; ++k) {
            const int q   = k * 64 + L;
            const int row = q >> 1;
            const int f4  = q & 1;
            const float4 v = *reinterpret_cast<const float4*>(
                &acts[(blk + row) * 64 + tc * 2 + f4 * 4]);
            *reinterpret_cast<float4*>(&abuf[row * 8 + ((f4 * 4) ^ (row & 4))]) = v;
        }

        #pragma unroll
        for (int tl = 0; tl < 4; ++tl) {
            const float2 act = *reinterpret_cast<const float2*>(
                &abuf[L * 8 + ((2 * tl) ^ (L & 4))]);
            const float ax = act.x, ay = act.y;

            // raw HW sin/cos (input in revolutions; psi in [-pi,pi] -> in range)
            const float rev = s4 * INV2PI;
            const float sn = __builtin_amdgcn_sinf(rev);
            const float c  = __builtin_amdgcn_cosf(rev);

            const float Vx = s1 * c + s3 * sn;
            const float v3 = c * s3 - sn * s1;
            const float v5 = s5;

            const float inv_mvx  = __builtin_amdgcn_rcpf(MF * Vx);
            const float inv_izvx = __builtin_amdgcn_rcpf(IZF * Vx);
            const float a33 = A33N * inv_mvx;
            const float a35 = -Vx + A35N * inv_mvx;
            const float a53 = A53N * inv_izvx;
            const float a55 = A55N * inv_izvx;

            const float d0 = Vx;
            float       d1 = (thr - THR_OFF) * THR_RAT;
            const float d2 = v3;
            float       d3 = a33 * v3 + a35 * v5 + ST1 * steer;
            const float d4 = v5;
            float       d5 = a53 * v3 + a55 * v5 + ST5 * steer;

            if (rnn) {
                // ---- layer 1 via MFMA, 3-level compensated (6 MFMA/tile) ----
                f32x4 acc[4];
                #pragma unroll
                for (int n = 0; n < 4; ++n) {
                    U4F bh; bh.u = *reinterpret_cast<const uint4*>(X + roffv[n]);
                    U4F bm; bm.u = *reinterpret_cast<const uint4*>(X + 4096 + roffv[n]);
                    U4F bl; bl.u = *reinterpret_cast<const uint4*>(X + 8192 + roffv[n]);
                    f32x4 a = __builtin_amdgcn_mfma_f32_16x16x32_bf16(Ah[tl], bl.f, zero4, 0, 0, 0);
                    a = __builtin_amdgcn_mfma_f32_16x16x32_bf16(Al[tl], bh.f, a, 0, 0, 0);
                    a = __builtin_amdgcn_mfma_f32_16x16x32_bf16(Am[tl], bm.f, a, 0, 0, 0);
                    a = __builtin_amdgcn_mfma_f32_16x16x32_bf16(Am[tl], bh.f, a, 0, 0, 0);
                    a = __builtin_amdgcn_mfma_f32_16x16x32_bf16(Ah[tl], bm.f, a, 0, 0, 0);
                    acc[n] = __builtin_amdgcn_mfma_f32_16x16x32_bf16(Ah[tl], bh.f, a, 0, 0, 0);
                }
                // y1 rows g*4+r per tile; layer-2 partials then transpose-reduce
                float p0[4], p1[4], p2[4];
                #pragma unroll
                for (int n = 0; n < 4; ++n) {
                    float q0 = 0.f, q1 = 0.f, q2 = 0.f;
                    #pragma unroll
                    for (int r = 0; r < 4; ++r) {
                        const float y = fast_tanh(acc[n][r] + b1s[r]);
                        q0 = fmaf(w2s[0][r], y, q0);
                        q1 = fmaf(w2s[1][r], y, q1);
                        q2 = fmaf(w2s[2][r], y, q2);
                    }
                    p0[n] = q0; p1[n] = q1; p2[n] = q2;
                }
                float z0, z1, z2;
                #pragma unroll
                for (int c3 = 0; c3 < 3; ++c3) {
                    const float* p = (c3 == 0) ? p0 : (c3 == 1) ? p1 : p2;
                    const float own = bb1 ? (bb0 ? p[3] : p[2]) : (bb0 ? p[1] : p[0]);
                    const float x1  = bb1 ? (bb0 ? p[2] : p[3]) : (bb0 ? p[0] : p[1]);
                    const float x2  = bb1 ? (bb0 ? p[1] : p[0]) : (bb0 ? p[3] : p[2]);
                    const float x3  = bb1 ? (bb0 ? p[0] : p[1]) : (bb0 ? p[2] : p[3]);
                    const float a = own + __shfl_xor(x1, 16, 64);
                    const float b = x2  + __shfl_xor(x3, 16, 64);
                    const float T = a + __shfl_xor(b, 32, 64);
                    if (c3 == 0) z0 = T; else if (c3 == 1) z1 = T; else z2 = T;
                }
                d1 += fast_tanh(z0 + bias2_0) * R0M;
                d3 += fast_tanh(z1 + bias2_1) * R1M;
                d5 += fast_tanh(z2 + bias2_2) * R2I;
            }

            const float ns0 = s0 + (c * d0 - sn * d2) * DT;
            const float ns1 = s1 + (c * d1 - sn * d3) * DT;
            const float ns2 = s2 + (sn * d0 + c * d2) * DT;
            const float ns3 = s3 + (sn * d1 + c * d3) * DT;
            float aa = s4 + d4 * DT + PI_F;
            aa = aa - floorf(aa * INV2PI) * TWOPI;
            const float ns4 = aa - PI_F;
            const float ns5 = s5 + d5 * DT;

            // stage outputs (elem-major, xor-swizzled float4 slots)
            const int c4b = (tl & 1) * 2;
            *reinterpret_cast<float4*>(&sbuf[L * 16 + 4 * ((c4b + 0) ^ (L & 3))]) =
                make_float4(ns0, ns1, ns2, ns3);
            *reinterpret_cast<float4*>(&sbuf[L * 16 + 4 * ((c4b + 1) ^ (L & 3))]) =
                make_float4(ns4, ns5, ax, ay);

            if (rnn) {
                split3_store(X, wboff ^ (tl * 16), ns0, ns1, ns2, ns3, ns4, ns5, ax, ay);
            }

            s0 = ns0; s1 = ns1; s2 = ns2; s3 = ns3;
            s4 = ns4; s5 = ns5; thr = ax; steer = ay;

            // ---- flush 2-step chunk (64 B/elem) ----
            if (tl & 1) {
                const int t2 = tc + tl - 1;
                #pragma unroll
                for (int k = 0; k < 4; ++k) {
                    const int q   = k * 64 + L;
                    const int row = q >> 2;
                    const int f   = q & 3;
                    const float4 v = *reinterpret_cast<const float4*>(
                        &sbuf[row * 16 + 4 * (f ^ (row & 3))]);
                    *reinterpret_cast<float4*>(&out[(blk + row) * 256 + t2 * 8 + f * 4]) = v;
                }
            }
        }
    }
}

} // namespace

extern "C" void kernel_launch(void* const* d_in, const int* in_sizes, int n_in,
                              void* d_out, int out_size, void* d_ws, size_t ws_size,
                              hipStream_t stream) {
    const float* fs = (const float*)d_in[0];
    const float* ac = (const float*)d_in[1];
    const float* w1 = (const float*)d_in[2];
    const float* b1 = (const float*)d_in[3];
    const float* w2 = (const float*)d_in[4];
    const float* b2 = (const float*)d_in[5];
    const int*   en = (const int*)d_in[6];
    float* out = (float*)d_out;
    unsigned* ws = (unsigned*)d_ws;

    hipLaunchKernelGGL(prep_kernel, dim3(1), dim3(256), 0, stream, w1, ws);

    dim3 grid(B_TOTAL / 64), block(64);
    hipLaunchKernelGGL(rollout_kernel, grid, block, 0, stream,
                       fs, ac, ws, b1, w2, b2, en, out);
}

// Round 15
// 73.192 us; speedup vs baseline: 1.5040x; 1.0162x over previous
//
#include <hip/hip_runtime.h>
#include <math.h>

namespace {

typedef short  bf16x8 __attribute__((ext_vector_type(8)));
typedef float  f32x4  __attribute__((ext_vector_type(4)));

constexpr int B_TOTAL = 131072;
constexpr int T_STEPS = 32;

constexpr double dG   = 9.81;
constexpr double dM   = 0.1667;
constexpr double dCAF = 5.0 * 0.25 * dM * dG;
constexpr double dCAR = dCAF;
constexpr double dLF  = 0.09 - 0.036;
constexpr double dLR  = 0.036;
constexpr double dIZ  = 0.000267;

constexpr float A33N = (float)(-(2.0 * dCAF + 2.0 * dCAR));
constexpr float A35N = (float)(-(2.0 * dCAF * dLF - 2.0 * dCAR * dLR));
constexpr float A53N = (float)(-(2.0 * dLF * dCAF - 2.0 * dLR * dCAR));
constexpr float A55N = (float)(-(2.0 * dLF * dLF * dCAF + 2.0 * dLR * dLR * dCAR));
constexpr float ST1  = (float)(2.0 * dCAF / dM);
constexpr float ST5  = (float)(2.0 * dLF * dCAF / dIZ);
constexpr float MF   = (float)dM;
constexpr float IZF  = (float)dIZ;
constexpr float R0M  = (float)(0.05 * dG / dM);
constexpr float R1M  = (float)(0.05 * dG / dM);
constexpr float R2I  = (float)(0.05 * dG * 0.2 / dIZ);
constexpr float THR_OFF = 0.24f;
constexpr float THR_RAT = 6.98f;
constexpr float DT    = 0.01f;
constexpr float PI_F  = (float)3.14159265358979323846;
constexpr float TWOPI = (float)(2.0 * 3.14159265358979323846);
constexpr float INV2PI = (float)(1.0 / (2.0 * 3.14159265358979323846));
constexpr float TWO_LOG2E = 2.8853900817779268f;

__device__ __forceinline__ float fast_tanh(float x) {
    const float e = __builtin_amdgcn_exp2f(x * TWO_LOG2E);
    return fmaf(-2.0f, __builtin_amdgcn_rcpf(e + 1.0f), 1.0f);
}

__device__ __forceinline__ unsigned bf16_rne_u(float f) {
    unsigned u = __float_as_uint(f);
    return (u + 0x7fffu + ((u >> 16) & 1u)) >> 16;
}

__device__ __forceinline__ unsigned pk_bf16(float lo, float hi) {
    unsigned r;
    asm("v_cvt_pk_bf16_f32 %0, %1, %2" : "=v"(r) : "v"(lo), "v"(hi));
    return r;
}
__device__ __forceinline__ float bfl(unsigned p) { return __uint_as_float(p << 16); }
__device__ __forceinline__ float bfh(unsigned p) { return __uint_as_float(p & 0xffff0000u); }

union U4F { uint4 u; bf16x8 f; };

// ---- prep: A-fragments (W1 16x32) for 4 rotations x 3 split levels.
__global__ void prep_kernel(const float* __restrict__ w1, unsigned* __restrict__ ws) {
    const int i = threadIdx.x;
    if (i >= 256) return;
    const int p = i >> 6, L = i & 63;
    const int row = L & 15, g = L >> 4;
    const int pos = (g - p) & 3;
    unsigned hd[4], md[4], ld[4];
    #pragma unroll
    for (int d = 0; d < 4; ++d) {
        unsigned hh[2], mm[2], ll[2];
        #pragma unroll
        for (int s = 0; s < 2; ++s) {
            const float v = w1[row * 32 + pos * 8 + 2 * d + s];
            const unsigned h = bf16_rne_u(v);
            const float r1 = v - __uint_as_float(h << 16);
            const unsigned m = bf16_rne_u(r1);
            const float r2 = r1 - __uint_as_float(m << 16);
            const unsigned l = bf16_rne_u(r2);
            hh[s] = h; mm[s] = m; ll[s] = l;
        }
        hd[d] = hh[0] | (hh[1] << 16);
        md[d] = mm[0] | (mm[1] << 16);
        ld[d] = ll[0] | (ll[1] << 16);
    }
    uint4* w4 = reinterpret_cast<uint4*>(ws);
    w4[(p * 3 + 0) * 64 + L] = make_uint4(hd[0], hd[1], hd[2], hd[3]);
    w4[(p * 3 + 1) * 64 + L] = make_uint4(md[0], md[1], md[2], md[3]);
    w4[(p * 3 + 2) * 64 + L] = make_uint4(ld[0], ld[1], ld[2], ld[3]);
}

__device__ __forceinline__ int xbase(int e) { return (e * 64) ^ ((e & 7) << 4); }

// 3-level split of one timestep row (8 f32) -> X (hi +0, mid +4096, lo +8192)
__device__ __forceinline__ void split3_store(
    char* X, int off,
    float v0, float v1, float v2, float v3, float v4, float v5, float v6, float v7)
{
    const unsigned h0 = pk_bf16(v0, v1), h1 = pk_bf16(v2, v3);
    const unsigned h2 = pk_bf16(v4, v5), h3 = pk_bf16(v6, v7);
    const float r0 = v0 - bfl(h0), r1 = v1 - bfh(h0);
    const float r2 = v2 - bfl(h1), r3 = v3 - bfh(h1);
    const float r4 = v4 - bfl(h2), r5 = v5 - bfh(h2);
    const float r6 = v6 - bfl(h3), r7 = v7 - bfh(h3);
    const unsigned m0 = pk_bf16(r0, r1), m1 = pk_bf16(r2, r3);
    const unsigned m2 = pk_bf16(r4, r5), m3 = pk_bf16(r6, r7);
    const unsigned l0 = pk_bf16(r0 - bfl(m0), r1 - bfh(m0));
    const unsigned l1 = pk_bf16(r2 - bfl(m1), r3 - bfh(m1));
    const unsigned l2 = pk_bf16(r4 - bfl(m2), r5 - bfh(m2));
    const unsigned l3 = pk_bf16(r6 - bfl(m3), r7 - bfh(m3));
    *reinterpret_cast<uint4*>(X + off)        = make_uint4(h0, h1, h2, h3);
    *reinterpret_cast<uint4*>(X + 4096 + off) = make_uint4(m0, m1, m2, m3);
    *reinterpret_cast<uint4*>(X + 8192 + off) = make_uint4(l0, l1, l2, l3);
}

__global__ __launch_bounds__(64, 2)
void rollout_kernel(const float* __restrict__ fs,     // B x 4 x 8
                    const float* __restrict__ acts,   // B x 32 x 2
                    const unsigned* __restrict__ ws,  // A-fragments (prep)
                    const float* __restrict__ b1g,    // 16
                    const float* __restrict__ w2g,    // 3 x 16
                    const float* __restrict__ b2g,    // 3
                    const int*   __restrict__ en,     // 1
                    float*       __restrict__ out)    // B x 32 x 8
{
    __shared__ char  X[12288];            // 12 KB window: hi | mid | lo
    __shared__ float abuf[64 * 8];        // 2 KB  actions, 4 steps
    __shared__ float sbuf[64 * 16];       // 4 KB  outputs, 2 steps
    // total 18 KB -> 8 single-wave blocks/CU

    const int L = threadIdx.x;            // lane = owned element
    const int g = L >> 4;                 // k-group / D-row-group
    const size_t blk = (size_t)blockIdx.x * 64;

    const int rnn = *en;

    // ---- loop-invariant registers ----
    bf16x8 Ah[4], Am[4], Al[4];
    {
        const uint4* w4 = reinterpret_cast<const uint4*>(ws);
        #pragma unroll
        for (int p = 0; p < 4; ++p) {
            U4F a; a.u = w4[(p * 3 + 0) * 64 + L]; Ah[p] = a.f;
            U4F b; b.u = w4[(p * 3 + 1) * 64 + L]; Am[p] = b.f;
            U4F c; c.u = w4[(p * 3 + 2) * 64 + L]; Al[p] = c.f;
        }
    }
    float b1s[4];
    #pragma unroll
    for (int r = 0; r < 4; ++r) b1s[r] = b1g[g * 4 + r];
    float w2s[3][4];
    #pragma unroll
    for (int c = 0; c < 3; ++c)
        #pragma unroll
        for (int r = 0; r < 4; ++r) w2s[c][r] = w2g[c * 16 + g * 4 + r];
    const float bias2_0 = b2g[0], bias2_1 = b2g[1], bias2_2 = b2g[2];

    // hoisted LDS offsets
    int roffv[4];
    #pragma unroll
    for (int n = 0; n < 4; ++n) roffv[n] = xbase(16 * n + (L & 15)) ^ (g * 16);
    const int wboff = xbase(L);

    // action staging addresses (lane-fixed)
    const int q0r = L >> 1,        q0f = (L & 1) * 4;          // k=0
    const int q1r = (64 + L) >> 1, q1f = (L & 1) * 4;          // k=1
    const int aw0 = q0r * 8 + (q0f ^ (q0r & 4));
    const int aw1 = q1r * 8 + (q1f ^ (q1r & 4));

    // ---- init: own element's 4 history rows -> X tiles + state regs ----
    float s0, s1, s2, s3, s4, s5, thr, steer;
    {
        const float4* ip = reinterpret_cast<const float4*>(fs + (blk + L) * 32);
        #pragma unroll
        for (int rr = 0; rr < 4; ++rr) {
            const float4 va = ip[rr * 2], vb = ip[rr * 2 + 1];
            split3_store(X, wboff ^ (rr * 16), va.x, va.y, va.z, va.w, vb.x, vb.y, vb.z, vb.w);
            if (rr == 3) {
                s0 = va.x; s1 = va.y; s2 = va.z; s3 = va.w;
                s4 = vb.x; s5 = vb.y; thr = vb.z; steer = vb.w;
            }
        }
    }

    // prologue: issue chunk-0 action loads (coalesced pairs)
    float4 ga0 = *reinterpret_cast<const float4*>(&acts[(blk + q0r) * 64 + q0f]);
    float4 ga1 = *reinterpret_cast<const float4*>(&acts[(blk + q1r) * 64 + q1f]);

    const f32x4 zero4 = {0.f, 0.f, 0.f, 0.f};

    for (int tc = 0; tc < T_STEPS; tc += 4) {
        // ---- stage the in-flight action data, read own 4 steps to regs ----
        *reinterpret_cast<float4*>(&abuf[aw0]) = ga0;
        *reinterpret_cast<float4*>(&abuf[aw1]) = ga1;
        const float4 av0 = *reinterpret_cast<const float4*>(&abuf[L * 8 + (0 ^ (L & 4))]);
        const float4 av1 = *reinterpret_cast<const float4*>(&abuf[L * 8 + (4 ^ (L & 4))]);
        // issue next chunk's loads (latency hidden under 4 steps of compute)
        if (tc + 4 < T_STEPS) {
            ga0 = *reinterpret_cast<const float4*>(&acts[(blk + q0r) * 64 + (tc + 4) * 2 + q0f]);
            ga1 = *reinterpret_cast<const float4*>(&acts[(blk + q1r) * 64 + (tc + 4) * 2 + q1f]);
        }

        #pragma unroll
        for (int tl = 0; tl < 4; ++tl) {
            const float ax = (tl == 0) ? av0.x : (tl == 1) ? av0.z : (tl == 2) ? av1.x : av1.z;
            const float ay = (tl == 0) ? av0.y : (tl == 1) ? av0.w : (tl == 2) ? av1.y : av1.w;

            // raw HW sin/cos (input in revolutions; psi in [-pi,pi] -> in range)
            const float rev = s4 * INV2PI;
            const float sn = __builtin_amdgcn_sinf(rev);
            const float c  = __builtin_amdgcn_cosf(rev);

            const float Vx = s1 * c + s3 * sn;
            const float v3 = c * s3 - sn * s1;
            const float v5 = s5;

            const float inv_mvx  = __builtin_amdgcn_rcpf(MF * Vx);
            const float inv_izvx = __builtin_amdgcn_rcpf(IZF * Vx);
            const float a33 = A33N * inv_mvx;
            const float a35 = -Vx + A35N * inv_mvx;
            const float a53 = A53N * inv_izvx;
            const float a55 = A55N * inv_izvx;

            const float d0 = Vx;
            float       d1 = (thr - THR_OFF) * THR_RAT;
            const float d2 = v3;
            float       d3 = a33 * v3 + a35 * v5 + ST1 * steer;
            const float d4 = v5;
            float       d5 = a53 * v3 + a55 * v5 + ST5 * steer;

            if (rnn) {
                // ---- layer 1 via MFMA, 3-level compensated (6 MFMA/tile) ----
                f32x4 acc[4];
                #pragma unroll
                for (int n = 0; n < 4; ++n) {
                    U4F bh; bh.u = *reinterpret_cast<const uint4*>(X + roffv[n]);
                    U4F bm; bm.u = *reinterpret_cast<const uint4*>(X + 4096 + roffv[n]);
                    U4F bl; bl.u = *reinterpret_cast<const uint4*>(X + 8192 + roffv[n]);
                    f32x4 a = __builtin_amdgcn_mfma_f32_16x16x32_bf16(Ah[tl], bl.f, zero4, 0, 0, 0);
                    a = __builtin_amdgcn_mfma_f32_16x16x32_bf16(Al[tl], bh.f, a, 0, 0, 0);
                    a = __builtin_amdgcn_mfma_f32_16x16x32_bf16(Am[tl], bm.f, a, 0, 0, 0);
                    a = __builtin_amdgcn_mfma_f32_16x16x32_bf16(Am[tl], bh.f, a, 0, 0, 0);
                    a = __builtin_amdgcn_mfma_f32_16x16x32_bf16(Ah[tl], bm.f, a, 0, 0, 0);
                    acc[n] = __builtin_amdgcn_mfma_f32_16x16x32_bf16(Ah[tl], bh.f, a, 0, 0, 0);
                }
                float p0[4], p1[4], p2[4];
                #pragma unroll
                for (int n = 0; n < 4; ++n) {
                    float q0 = 0.f, q1 = 0.f, q2 = 0.f;
                    #pragma unroll
                    for (int r = 0; r < 4; ++r) {
                        const float y = fast_tanh(acc[n][r] + b1s[r]);
                        q0 = fmaf(w2s[0][r], y, q0);
                        q1 = fmaf(w2s[1][r], y, q1);
                        q2 = fmaf(w2s[2][r], y, q2);
                    }
                    p0[n] = q0; p1[n] = q1; p2[n] = q2;
                }
                const bool bb0 = (g & 1) != 0, bb1 = (g & 2) != 0;
                float z0, z1, z2;
                #pragma unroll
                for (int c3 = 0; c3 < 3; ++c3) {
                    const float* p = (c3 == 0) ? p0 : (c3 == 1) ? p1 : p2;
                    const float own = bb1 ? (bb0 ? p[3] : p[2]) : (bb0 ? p[1] : p[0]);
                    const float x1  = bb1 ? (bb0 ? p[2] : p[3]) : (bb0 ? p[0] : p[1]);
                    const float x2  = bb1 ? (bb0 ? p[1] : p[0]) : (bb0 ? p[3] : p[2]);
                    const float x3  = bb1 ? (bb0 ? p[0] : p[1]) : (bb0 ? p[2] : p[3]);
                    const float a = own + __shfl_xor(x1, 16, 64);
                    const float b = x2  + __shfl_xor(x3, 16, 64);
                    const float T = a + __shfl_xor(b, 32, 64);
                    if (c3 == 0) z0 = T; else if (c3 == 1) z1 = T; else z2 = T;
                }
                d1 += fast_tanh(z0 + bias2_0) * R0M;
                d3 += fast_tanh(z1 + bias2_1) * R1M;
                d5 += fast_tanh(z2 + bias2_2) * R2I;
            }

            const float ns0 = s0 + (c * d0 - sn * d2) * DT;
            const float ns1 = s1 + (c * d1 - sn * d3) * DT;
            const float ns2 = s2 + (sn * d0 + c * d2) * DT;
            const float ns3 = s3 + (sn * d1 + c * d3) * DT;
            float aa = s4 + d4 * DT + PI_F;
            aa = aa - floorf(aa * INV2PI) * TWOPI;
            const float ns4 = aa - PI_F;
            const float ns5 = s5 + d5 * DT;

            // stage outputs (elem-major, xor-swizzled float4 slots)
            const int c4b = (tl & 1) * 2;
            *reinterpret_cast<float4*>(&sbuf[L * 16 + 4 * ((c4b + 0) ^ (L & 3))]) =
                make_float4(ns0, ns1, ns2, ns3);
            *reinterpret_cast<float4*>(&sbuf[L * 16 + 4 * ((c4b + 1) ^ (L & 3))]) =
                make_float4(ns4, ns5, ax, ay);

            if (rnn) {
                split3_store(X, wboff ^ (tl * 16), ns0, ns1, ns2, ns3, ns4, ns5, ax, ay);
            }

            s0 = ns0; s1 = ns1; s2 = ns2; s3 = ns3;
            s4 = ns4; s5 = ns5; thr = ax; steer = ay;

            // ---- flush 2-step chunk (64 B/elem) ----
            if (tl & 1) {
                const int t2 = tc + tl - 1;
                #pragma unroll
                for (int k = 0; k < 4; ++k) {
                    const int q   = k * 64 + L;
                    const int row = q >> 2;
                    const int f   = q & 3;
                    const float4 v = *reinterpret_cast<const float4*>(
                        &sbuf[row * 16 + 4 * (f ^ (row & 3))]);
                    *reinterpret_cast<float4*>(&out[(blk + row) * 256 + t2 * 8 + f * 4]) = v;
                }
            }
        }
    }
}

} // namespace

extern "C" void kernel_launch(void* const* d_in, const int* in_sizes, int n_in,
                              void* d_out, int out_size, void* d_ws, size_t ws_size,
                              hipStream_t stream) {
    const float* fs = (const float*)d_in[0];
    const float* ac = (const float*)d_in[1];
    const float* w1 = (const float*)d_in[2];
    const float* b1 = (const float*)d_in[3];
    const float* w2 = (const float*)d_in[4];
    const float* b2 = (const float*)d_in[5];
    const int*   en = (const int*)d_in[6];
    float* out = (float*)d_out;
    unsigned* ws = (unsigned*)d_ws;

    hipLaunchKernelGGL(prep_kernel, dim3(1), dim3(256), 0, stream, w1, ws);

    dim3 grid(B_TOTAL / 64), block(64);
    hipLaunchKernelGGL(rollout_kernel, grid, block, 0, stream,
                       fs, ac, ws, b1, w2, b2, en, out);
}